// Round 3
// baseline (71.725 us; speedup 1.0000x reference)
//
#include <hip/hip_runtime.h>
#include <math.h>

#define NB 16
#define NQ 900
#define NC 80
#define EPSV 1e-7f
#define IOU_THR 0.1f
#define CHUNKS 15          // blocks per batch
#define SPB 60             // student queries per block
#define NBLK (NB * CHUNKS) // 240

__device__ __forceinline__ float sigm(float x) { return 1.0f / (1.0f + __expf(-x)); }

__global__ __launch_bounds__(256, 2) void fused_detr(
    const float* __restrict__ s_logits,
    const float* __restrict__ s_boxes,
    const float* __restrict__ t_logits,
    const float* __restrict__ t_boxes,
    const int*   __restrict__ tn_p,
    float* __restrict__ out,
    int*   bar_batch,                 // [16]  zeroed by memset node
    int*   bar_done,                  // [1]   zeroed by memset node
    int*   __restrict__ g_conf0,      // [16]
    float4* __restrict__ g_part,      // [240]
    float* __restrict__ g_max_iou,    // [NB*NQ]
    float* __restrict__ g_l1,         // [NB*NQ]
    float* __restrict__ g_giou)       // [NB*NQ]
{
    __shared__ float4 tcor[NQ];   // x1, x2, y1, y2
    __shared__ float  tarea[NQ];
    __shared__ int    lidx[SPB];  // this block's max_idx (local consumption only)
    __shared__ float4 spart[4];
    __shared__ int    lastf;

    const int bid   = blockIdx.x;
    const int b     = bid / CHUNKS;
    const int chunk = bid - b * CHUNKS;
    const int tid   = threadIdx.x;

    // ---- stage teacher boxes for batch b ----
    const float4* tb = (const float4*)(t_boxes + b * NQ * 4);
    for (int i = tid; i < NQ; i += 256) {
        float4 t = tb[i];
        float hw = t.z * 0.5f, hh = t.w * 0.5f;
        tcor[i]  = make_float4(t.x - hw, t.x + hw, t.y - hh, t.y + hh);
        tarea[i] = t.z * t.w;
    }
    // conf0[b] = sigmoid(max(t_logits[b,0,:])) > 0.2  (one wave of chunk-0 block)
    if (chunk == 0 && tid < 64) {
        const float* tl = t_logits + b * NQ * NC;
        float m = tl[tid];
        if (tid < NC - 64) m = fmaxf(m, tl[tid + 64]);
        for (int s = 32; s >= 1; s >>= 1) m = fmaxf(m, __shfl_xor(m, s, 64));
        if (tid == 0) g_conf0[b] = (sigm(m) > 0.2f) ? 1 : 0;
    }
    __syncthreads();

    // ---- phase 1: argmax IoU over 900 teachers, 4 lanes per student ----
    const int s  = tid >> 2;          // 0..63 (active < 60)
    const int tc = tid & 3;           // teacher phase
    const int sq = chunk * SPB + s;
    float best = -1.0f; int bidx = 0;
    float4 sb = make_float4(0.f, 0.f, 0.f, 0.f);
    float sx1 = 0.f, sx2 = 0.f, sy1 = 0.f, sy2 = 0.f, sarea = 0.f;
    if (s < SPB) {
        sb = ((const float4*)(s_boxes + b * NQ * 4))[sq];
        float shw = sb.z * 0.5f, shh = sb.w * 0.5f;
        sx1 = sb.x - shw; sx2 = sb.x + shw;
        sy1 = sb.y - shh; sy2 = sb.y + shh;
        sarea = sb.z * sb.w;
        #pragma unroll 9
        for (int i = 0; i < 225; ++i) {
            int t = tc + (i << 2);     // covers [0,900) exactly
            float4 c = tcor[t];
            float iw = fminf(sx2, c.y) - fmaxf(sx1, c.x);
            float ih = fminf(sy2, c.w) - fmaxf(sy1, c.z);
            float inter = fmaxf(iw, 0.0f) * fmaxf(ih, 0.0f);
            float uni = sarea + tarea[t] - inter + EPSV;
            float iou = inter * __frcp_rn(uni);
            if (iou > best) { best = iou; bidx = t; }   // strictly greater
        }
    }
    // combine 4 phases; ties -> lower teacher index (argmax first-occurrence)
    for (int m = 1; m <= 2; m <<= 1) {
        float ov = __shfl_xor(best, m, 64);
        int   oi = __shfl_xor(bidx, m, 64);
        if (ov > best || (ov == best && oi < bidx)) { best = ov; bidx = oi; }
    }
    if (s < SPB && tc == 0) {
        int o = b * NQ + sq;
        g_max_iou[o] = best;
        lidx[s] = bidx;
        // L1 and (1 - GIoU) vs teacher box 0
        float4 t0 = tb[0];
        float4 c  = tcor[0];
        float iw = fminf(sx2, c.y) - fmaxf(sx1, c.x);
        float ih = fminf(sy2, c.w) - fmaxf(sy1, c.z);
        float inter = fmaxf(iw, 0.0f) * fmaxf(ih, 0.0f);
        float uni = sarea + tarea[0] - inter + EPSV;
        float iou = inter / uni;
        float cw = fmaxf(sx2, c.y) - fminf(sx1, c.x);
        float ch = fmaxf(sy2, c.w) - fminf(sy1, c.z);
        float carea = cw * ch + EPSV;
        g_giou[o] = 1.0f - (iou - (carea - uni) / carea);
        g_l1[o] = fabsf(sb.x - t0.x) + fabsf(sb.y - t0.y) +
                  fabsf(sb.z - t0.z) + fabsf(sb.w - t0.w);
    }

    // ---- batch-local barrier (15 blocks, device-scope) ----
    __syncthreads();
    if (tid == 0) {
        __hip_atomic_fetch_add(&bar_batch[b], 1, __ATOMIC_RELEASE, __HIP_MEMORY_SCOPE_AGENT);
        while (__hip_atomic_load(&bar_batch[b], __ATOMIC_ACQUIRE, __HIP_MEMORY_SCOPE_AGENT) < CHUNKS) {}
    }
    __syncthreads();

    // ---- phase 2: BCE + conf-any + flag-gated l1/giou for rows [chunk*60, +60) ----
    const int wv = tid >> 6, lane = tid & 63;
    const int conf0b = g_conf0[b];
    float bcea = 0.f, l1a = 0.f, ga = 0.f; int confb = 0;
    #pragma unroll 3
    for (int m = 0; m < 15; ++m) {
        int k   = wv * 15 + m;                 // 0..59
        int row = b * NQ + chunk * SPB + k;
        int j   = lidx[k];                     // flat idx -> batch-0 teacher row (ref quirk)
        const float* srow = s_logits + row * NC;
        const float* trow = t_logits + row * NC;
        const float* grow = t_logits + j * NC;
        float s0 = srow[lane], t0 = trow[lane], g0 = grow[lane];
        float bce = fmaxf(s0, 0.f) + __logf(1.0f + __expf(-fabsf(s0)))
                  - s0 * __frcp_rn(1.0f + __expf(-g0));
        float tmax = t0;
        if (lane < NC - 64) {
            float s1 = srow[lane + 64], t1 = trow[lane + 64], g1 = grow[lane + 64];
            bce += fmaxf(s1, 0.f) + __logf(1.0f + __expf(-fabsf(s1)))
                 - s1 * __frcp_rn(1.0f + __expf(-g1));
            tmax = fmaxf(tmax, t1);
        }
        for (int sft = 32; sft >= 1; sft >>= 1) {
            bce += __shfl_xor(bce, sft, 64);
            tmax = fmaxf(tmax, __shfl_xor(tmax, sft, 64));
        }
        if (lane == 0) {
            bcea += bce * (1.0f / (float)NC);
            confb |= (sigm(tmax) > 0.2f) ? 1 : 0;
            float mi = g_max_iou[b * NQ + j];  // student-indexed gather (ref quirk)
            if (mi > IOU_THR && conf0b) {
                l1a += g_l1[b * NQ + j];
                ga  += g_giou[b * NQ + j];
            }
        }
    }
    if (lane == 0) spart[wv] = make_float4(bcea, l1a, ga, (float)confb);
    __syncthreads();

    // ---- last-block finalize ----
    if (tid == 0) {
        float4 a = spart[0], bq = spart[1], c = spart[2], d = spart[3];
        g_part[bid] = make_float4(a.x + bq.x + c.x + d.x,
                                  a.y + bq.y + c.y + d.y,
                                  a.z + bq.z + c.z + d.z,
                                  fmaxf(fmaxf(a.w, bq.w), fmaxf(c.w, d.w)));
        int old = __hip_atomic_fetch_add(bar_done, 1, __ATOMIC_ACQ_REL, __HIP_MEMORY_SCOPE_AGENT);
        lastf = (old == NBLK - 1) ? 1 : 0;
    }
    __syncthreads();
    if (lastf && tid < 64) {
        float bs = 0.f, ls = 0.f, gs = 0.f, cs = 0.f;
        for (int i = tid; i < NBLK; i += 64) {
            float4 p = g_part[i];
            bs += p.x; ls += p.y; gs += p.z; cs = fmaxf(cs, p.w);
        }
        for (int sft = 32; sft >= 1; sft >>= 1) {
            bs += __shfl_xor(bs, sft, 64);
            ls += __shfl_xor(ls, sft, 64);
            gs += __shfl_xor(gs, sft, 64);
            cs  = fmaxf(cs, __shfl_xor(cs, sft, 64));
        }
        if (tid == 0) {
            float tn = (float)tn_p[0];
            float loss = (5.0f * ls + 2.0f * gs + bs) / tn;
            out[0] = (cs > 0.f) ? loss : 0.0f;
        }
    }
}

extern "C" void kernel_launch(void* const* d_in, const int* in_sizes, int n_in,
                              void* d_out, int out_size, void* d_ws, size_t ws_size,
                              hipStream_t stream) {
    const float* s_logits = (const float*)d_in[0];
    const float* s_boxes  = (const float*)d_in[1];
    const float* t_logits = (const float*)d_in[2];
    const float* t_boxes  = (const float*)d_in[3];
    const int*   tn       = (const int*)d_in[4];
    float* out = (float*)d_out;

    char* ws = (char*)d_ws;
    int*    bar_batch = (int*)(ws);             // 16 i32  @ 0
    int*    bar_done  = (int*)(ws + 64);        // 1 i32   @ 64
    int*    g_conf0   = (int*)(ws + 128);       // 16 i32  @ 128
    float4* g_part    = (float4*)(ws + 192);    // 240 f4  @ 192..4032
    float*  g_max_iou = (float*)(ws + 4096);    // 14400 f32
    float*  g_l1      = (float*)(ws + 61696);   // 14400 f32
    float*  g_giou    = (float*)(ws + 119296);  // 14400 f32

    // zero the barrier counters every call (graph-capture-legal, deterministic replays)
    hipMemsetAsync(ws, 0, 128, stream);
    fused_detr<<<NBLK, 256, 0, stream>>>(s_logits, s_boxes, t_logits, t_boxes, tn, out,
                                         bar_batch, bar_done, g_conf0, g_part,
                                         g_max_iou, g_l1, g_giou);
}

// Round 4
// 31.875 us; speedup vs baseline: 2.2501x; 2.2501x over previous
//
#include <hip/hip_runtime.h>
#include <math.h>

#define NB 16
#define NQ 900
#define NC 80
#define EPSV 1e-7f
#define IOU_THR 0.1f
#define SPB 16              // students per block
#define CHB 57              // blocks per batch (57*16 = 912 >= 900)

__device__ __forceinline__ float sigm(float x) { return 1.0f / (1.0f + __expf(-x)); }

// ---- K1: per-(b, 16 students): IoU argmax (16-lane split) + own-row BCE/conf ----
__global__ __launch_bounds__(256) void k_main(
    const float* __restrict__ s_logits,
    const float* __restrict__ s_boxes,
    const float* __restrict__ t_logits,
    const float* __restrict__ t_boxes,
    int*    __restrict__ g_idx,     // [NB*NQ]
    float*  __restrict__ g_v,       // [NB*NQ]  flag-gated 5*l1+2*(1-giou), else 0
    float2* __restrict__ g_part)    // [NB*CHB] (bce_sum, conf_any)
{
    __shared__ float4 tcor[NQ];     // x1, x2, y1, y2
    __shared__ float  tarea[NQ];
    __shared__ int    lidx[SPB];
    __shared__ float  sconf0;
    __shared__ float2 spart[4];

    const int bx  = blockIdx.x;     // 0..56
    const int b   = blockIdx.y;     // 0..15
    const int tid = threadIdx.x;

    // stage teacher boxes of batch b
    const float4* tb = (const float4*)(t_boxes + b * NQ * 4);
    for (int i = tid; i < NQ; i += 256) {
        float4 t = tb[i];
        float hw = t.z * 0.5f, hh = t.w * 0.5f;
        tcor[i]  = make_float4(t.x - hw, t.x + hw, t.y - hh, t.y + hh);
        tarea[i] = t.z * t.w;
    }
    // conf0[b] (redundant per block; one wave, ~100 cycles)
    if (tid < 64) {
        const float* tl = t_logits + b * NQ * NC;   // teacher row 0 of batch b
        float m = tl[tid];
        if (tid < NC - 64) m = fmaxf(m, tl[tid + 64]);
        for (int s = 32; s >= 1; s >>= 1) m = fmaxf(m, __shfl_xor(m, s, 64));
        if (tid == 0) sconf0 = (sigm(m) > 0.2f) ? 1.0f : 0.0f;
    }
    __syncthreads();

    // ---- argmax IoU over 900 teachers; 16 lanes per student ----
    const int s  = tid >> 4;        // 0..15
    const int tc = tid & 15;        // teacher phase
    const int sq = bx * SPB + s;
    const bool act = (sq < NQ);
    float best = -1.0f; int bidx = 0;
    float4 sb = make_float4(0.f, 0.f, 0.f, 0.f);
    float sx1 = 0.f, sx2 = 0.f, sy1 = 0.f, sy2 = 0.f, sarea = 0.f;
    if (act) {
        sb = ((const float4*)(s_boxes + b * NQ * 4))[sq];
        float shw = sb.z * 0.5f, shh = sb.w * 0.5f;
        sx1 = sb.x - shw; sx2 = sb.x + shw;
        sy1 = sb.y - shh; sy2 = sb.y + shh;
        sarea = sb.z * sb.w;
        #pragma unroll 4
        for (int i = 0; i < 57; ++i) {
            int t = tc + (i << 4);
            if (t < NQ) {
                float4 c = tcor[t];
                float iw = fminf(sx2, c.y) - fmaxf(sx1, c.x);
                float ih = fminf(sy2, c.w) - fmaxf(sy1, c.z);
                float inter = fmaxf(iw, 0.0f) * fmaxf(ih, 0.0f);
                float uni = sarea + tarea[t] - inter + EPSV;
                float iou = inter * __frcp_rn(uni);
                if (iou > best) { best = iou; bidx = t; }  // strictly greater
            }
        }
    }
    // combine 16 phases (xor within 16-lane groups); ties -> lower index
    for (int m = 1; m <= 8; m <<= 1) {
        float ov = __shfl_xor(best, m, 64);
        int   oi = __shfl_xor(bidx, m, 64);
        if (ov > best || (ov == best && oi < bidx)) { best = ov; bidx = oi; }
    }
    if (act && tc == 0) {
        int o = b * NQ + sq;
        g_idx[o] = bidx;
        lidx[s]  = bidx;
        // L1 and (1 - GIoU) vs teacher box 0
        float4 t0 = tb[0];
        float4 c  = tcor[0];
        float iw = fminf(sx2, c.y) - fmaxf(sx1, c.x);
        float ih = fminf(sy2, c.w) - fmaxf(sy1, c.z);
        float inter = fmaxf(iw, 0.0f) * fmaxf(ih, 0.0f);
        float uni = sarea + tarea[0] - inter + EPSV;
        float iou = inter / uni;
        float cw = fmaxf(sx2, c.y) - fminf(sx1, c.x);
        float ch = fmaxf(sy2, c.w) - fminf(sy1, c.z);
        float carea = cw * ch + EPSV;
        float giou1 = 1.0f - (iou - (carea - uni) / carea);
        float l1 = fabsf(sb.x - t0.x) + fabsf(sb.y - t0.y) +
                   fabsf(sb.z - t0.z) + fabsf(sb.w - t0.w);
        float v = 0.0f;
        if (sconf0 > 0.0f && best > IOU_THR) v = 5.0f * l1 + 2.0f * giou1;
        g_v[o] = v;
    }
    __syncthreads();

    // ---- BCE + conf for this block's 16 rows (wave w: rows w*4..w*4+3) ----
    const int wv = tid >> 6, lane = tid & 63;
    float bcea = 0.f, confb = 0.f;
    #pragma unroll
    for (int k = 0; k < 4; ++k) {
        int s2  = wv * 4 + k;
        int sq2 = bx * SPB + s2;
        if (sq2 < NQ) {
            int row = b * NQ + sq2;
            int j   = lidx[s2];                 // flat idx -> batch-0 teacher row (ref quirk)
            const float* srow = s_logits + row * NC;
            const float* trow = t_logits + row * NC;
            const float* grow = t_logits + j * NC;
            float s0 = srow[lane], t0 = trow[lane], g0 = grow[lane];
            float bce = fmaxf(s0, 0.f) + __logf(1.0f + __expf(-fabsf(s0)))
                      - s0 * __frcp_rn(1.0f + __expf(-g0));
            float tmax = t0;
            if (lane < NC - 64) {
                float s1 = srow[lane + 64], t1 = trow[lane + 64], g1 = grow[lane + 64];
                bce += fmaxf(s1, 0.f) + __logf(1.0f + __expf(-fabsf(s1)))
                     - s1 * __frcp_rn(1.0f + __expf(-g1));
                tmax = fmaxf(tmax, t1);
            }
            for (int sft = 32; sft >= 1; sft >>= 1) {
                bce  += __shfl_xor(bce, sft, 64);
                tmax  = fmaxf(tmax, __shfl_xor(tmax, sft, 64));
            }
            if (lane == 0) {
                bcea += bce * (1.0f / (float)NC);
                if (sigm(tmax) > 0.2f) confb = 1.0f;
            }
        }
    }
    if (lane == 0) spart[wv] = make_float2(bcea, confb);
    __syncthreads();
    if (tid == 0) {
        float2 a = spart[0], bq = spart[1], c = spart[2], d = spart[3];
        g_part[b * CHB + bx] = make_float2(a.x + bq.x + c.x + d.x,
                                           fmaxf(fmaxf(a.y, bq.y), fmaxf(c.y, d.y)));
    }
}

// ---- K2: single block — partial reduce + flag-gather + finalize ----
__global__ __launch_bounds__(1024) void k_final(
    const int*    __restrict__ g_idx,
    const float*  __restrict__ g_v,
    const float2* __restrict__ g_part,
    const int*    __restrict__ tn_p,
    float* __restrict__ out)
{
    const int tid = threadIdx.x;
    float bs = 0.f, ca = 0.f;
    if (tid < NB * CHB) { float2 p = g_part[tid]; bs = p.x; ca = p.y; }
    float vs = 0.f;
    #pragma unroll
    for (int k = 0; k < 15; ++k) {
        int i = tid + k * 1024;
        if (i < NB * NQ) {
            int j = g_idx[i];
            int b = i / NQ;
            vs += g_v[b * NQ + j];
        }
    }
    __shared__ float rb[16], rv[16], rc[16];
    const int wv = tid >> 6, lane = tid & 63;
    for (int m = 32; m >= 1; m >>= 1) {
        bs += __shfl_xor(bs, m, 64);
        vs += __shfl_xor(vs, m, 64);
        ca  = fmaxf(ca, __shfl_xor(ca, m, 64));
    }
    if (lane == 0) { rb[wv] = bs; rv[wv] = vs; rc[wv] = ca; }
    __syncthreads();
    if (tid == 0) {
        float sb = 0.f, sv = 0.f, sc = 0.f;
        for (int k = 0; k < 16; ++k) { sb += rb[k]; sv += rv[k]; sc = fmaxf(sc, rc[k]); }
        float tn = (float)tn_p[0];
        out[0] = (sc > 0.f) ? (sv + sb) / tn : 0.0f;
    }
}

extern "C" void kernel_launch(void* const* d_in, const int* in_sizes, int n_in,
                              void* d_out, int out_size, void* d_ws, size_t ws_size,
                              hipStream_t stream) {
    const float* s_logits = (const float*)d_in[0];
    const float* s_boxes  = (const float*)d_in[1];
    const float* t_logits = (const float*)d_in[2];
    const float* t_boxes  = (const float*)d_in[3];
    const int*   tn       = (const int*)d_in[4];
    float* out = (float*)d_out;

    char* ws = (char*)d_ws;
    int*    g_idx  = (int*)(ws);              // 14400 i32 @ 0
    float*  g_v    = (float*)(ws + 57600);    // 14400 f32
    float2* g_part = (float2*)(ws + 115200);  // 912 float2

    k_main<<<dim3(CHB, NB), 256, 0, stream>>>(s_logits, s_boxes, t_logits, t_boxes,
                                              g_idx, g_v, g_part);
    k_final<<<1, 1024, 0, stream>>>(g_idx, g_v, g_part, tn, out);
}

// Round 5
// 30.528 us; speedup vs baseline: 2.3495x; 1.0441x over previous
//
#include <hip/hip_runtime.h>
#include <math.h>

#define NB 16
#define NQ 900
#define NC 80
#define EPSV 1e-7f
#define IOU_THR 0.1f
#define SPB 16              // students per block
#define CHB 57              // blocks per batch (57*16 = 912 >= 900)

__device__ __forceinline__ float sigm(float x) { return 1.0f / (1.0f + __expf(-x)); }

// ---- K1: per-(b, 16 students): IoU argmax + cnt scatter + own-row BCE/conf ----
__global__ __launch_bounds__(256) void k_main(
    const float* __restrict__ s_logits,
    const float* __restrict__ s_boxes,
    const float* __restrict__ t_logits,
    const float* __restrict__ t_boxes,
    int*    __restrict__ g_cnt,     // [NB*NQ]  zeroed by memset node; cnt[b,j] += 1
    float*  __restrict__ g_v,       // [NB*NQ]  flag-gated 5*l1+2*(1-giou), else 0
    float2* __restrict__ g_part)    // [NB*CHB] (bce_sum, conf_any)
{
    __shared__ float4 tcor[NQ];     // x1, x2, y1, y2
    __shared__ float  tarea[NQ];
    __shared__ int    lidx[SPB];
    __shared__ float  sconf0;
    __shared__ float2 sres[SPB];    // per-row (bce_mean, conf)

    const int bx  = blockIdx.x;     // 0..56
    const int b   = blockIdx.y;     // 0..15
    const int tid = threadIdx.x;

    if (tid < SPB) sres[tid] = make_float2(0.f, 0.f);

    // stage teacher boxes of batch b
    const float4* tb = (const float4*)(t_boxes + b * NQ * 4);
    for (int i = tid; i < NQ; i += 256) {
        float4 t = tb[i];
        float hw = t.z * 0.5f, hh = t.w * 0.5f;
        tcor[i]  = make_float4(t.x - hw, t.x + hw, t.y - hh, t.y + hh);
        tarea[i] = t.z * t.w;
    }
    // conf0[b] (redundant per block; one wave)
    if (tid < 64) {
        const float* tl = t_logits + b * NQ * NC;   // teacher row 0 of batch b
        float m = tl[tid];
        if (tid < NC - 64) m = fmaxf(m, tl[tid + 64]);
        for (int s = 32; s >= 1; s >>= 1) m = fmaxf(m, __shfl_xor(m, s, 64));
        if (tid == 0) sconf0 = (sigm(m) > 0.2f) ? 1.0f : 0.0f;
    }
    __syncthreads();

    // ---- argmax IoU over 900 teachers; 16 lanes per student ----
    const int s  = tid >> 4;        // 0..15
    const int tc = tid & 15;        // teacher phase
    const int sq = bx * SPB + s;
    const bool act = (sq < NQ);
    float best = -1.0f; int bidx = 0;
    float4 sb = make_float4(0.f, 0.f, 0.f, 0.f);
    float sx1 = 0.f, sx2 = 0.f, sy1 = 0.f, sy2 = 0.f, sarea = 0.f;
    if (act) {
        sb = ((const float4*)(s_boxes + b * NQ * 4))[sq];
        float shw = sb.z * 0.5f, shh = sb.w * 0.5f;
        sx1 = sb.x - shw; sx2 = sb.x + shw;
        sy1 = sb.y - shh; sy2 = sb.y + shh;
        sarea = sb.z * sb.w;
        #pragma unroll 4
        for (int i = 0; i < 57; ++i) {
            int t = tc + (i << 4);
            if (t < NQ) {
                float4 c = tcor[t];
                float iw = fminf(sx2, c.y) - fmaxf(sx1, c.x);
                float ih = fminf(sy2, c.w) - fmaxf(sy1, c.z);
                float inter = fmaxf(iw, 0.0f) * fmaxf(ih, 0.0f);
                float uni = sarea + tarea[t] - inter + EPSV;
                float iou = inter * __frcp_rn(uni);
                if (iou > best) { best = iou; bidx = t; }  // strictly greater
            }
        }
    }
    // combine 16 phases; ties -> lower index (argmax first-occurrence)
    for (int m = 1; m <= 8; m <<= 1) {
        float ov = __shfl_xor(best, m, 64);
        int   oi = __shfl_xor(bidx, m, 64);
        if (ov > best || (ov == best && oi < bidx)) { best = ov; bidx = oi; }
    }
    if (act && tc == 0) {
        int o = b * NQ + sq;
        lidx[s] = bidx;
        atomicAdd(&g_cnt[b * NQ + bidx], 1);    // scatter-count (int, deterministic)
        // L1 and (1 - GIoU) vs teacher box 0
        float4 t0 = tb[0];
        float4 c  = tcor[0];
        float iw = fminf(sx2, c.y) - fmaxf(sx1, c.x);
        float ih = fminf(sy2, c.w) - fmaxf(sy1, c.z);
        float inter = fmaxf(iw, 0.0f) * fmaxf(ih, 0.0f);
        float uni = sarea + tarea[0] - inter + EPSV;
        float iou = inter / uni;
        float cw = fmaxf(sx2, c.y) - fminf(sx1, c.x);
        float ch = fmaxf(sy2, c.w) - fminf(sy1, c.z);
        float carea = cw * ch + EPSV;
        float giou1 = 1.0f - (iou - (carea - uni) / carea);
        float l1 = fabsf(sb.x - t0.x) + fabsf(sb.y - t0.y) +
                   fabsf(sb.z - t0.z) + fabsf(sb.w - t0.w);
        float v = 0.0f;
        if (sconf0 > 0.0f && best > IOU_THR) v = 5.0f * l1 + 2.0f * giou1;
        g_v[o] = v;
    }
    __syncthreads();

    // ---- BCE + conf: 16-lane group per row, all 16 rows in one pass ----
    const int wv  = tid >> 6, lane = tid & 63;
    const int grp = lane >> 4, tc2 = lane & 15;
    const int s2  = wv * 4 + grp;              // 0..15
    const int sq2 = bx * SPB + s2;
    if (sq2 < NQ) {
        int row = b * NQ + sq2;
        int j   = lidx[s2];                    // flat idx -> batch-0 teacher row (ref quirk)
        const float* srow = s_logits + row * NC;
        const float* trow = t_logits + row * NC;
        const float* grow = t_logits + j * NC;
        float bce = 0.f, tmax = -1e30f;
        #pragma unroll
        for (int e = 0; e < 5; ++e) {
            int c = e * 16 + tc2;
            float s0 = srow[c], t0 = trow[c], g0 = grow[c];
            bce += fmaxf(s0, 0.f) + __logf(1.0f + __expf(-fabsf(s0)))
                 - s0 * __frcp_rn(1.0f + __expf(-g0));
            tmax = fmaxf(tmax, t0);
        }
        for (int m = 8; m >= 1; m >>= 1) {
            bce  += __shfl_xor(bce, m, 64);
            tmax  = fmaxf(tmax, __shfl_xor(tmax, m, 64));
        }
        if (tc2 == 0)
            sres[s2] = make_float2(bce * (1.0f / (float)NC),
                                   (sigm(tmax) > 0.2f) ? 1.0f : 0.0f);
    }
    __syncthreads();
    if (tid == 0) {
        float bs = 0.f, ca = 0.f;
        #pragma unroll
        for (int k = 0; k < SPB; ++k) { bs += sres[k].x; ca = fmaxf(ca, sres[k].y); }
        g_part[b * CHB + bx] = make_float2(bs, ca);
    }
}

// ---- K2: single block — coalesced cnt·v dot + partial reduce + finalize ----
__global__ __launch_bounds__(1024) void k_final(
    const int*    __restrict__ g_cnt,
    const float*  __restrict__ g_v,
    const float2* __restrict__ g_part,
    const int*    __restrict__ tn_p,
    float* __restrict__ out)
{
    const int tid = threadIdx.x;
    float bs = 0.f, ca = 0.f;
    if (tid < NB * CHB) { float2 p = g_part[tid]; bs = p.x; ca = p.y; }
    float vs = 0.f;
    #pragma unroll
    for (int k = 0; k < 15; ++k) {
        int i = tid + k * 1024;
        if (i < NB * NQ) vs += (float)g_cnt[i] * g_v[i];   // coalesced, no indirection
    }
    __shared__ float rb[16], rv[16], rc[16];
    const int wv = tid >> 6, lane = tid & 63;
    for (int m = 32; m >= 1; m >>= 1) {
        bs += __shfl_xor(bs, m, 64);
        vs += __shfl_xor(vs, m, 64);
        ca  = fmaxf(ca, __shfl_xor(ca, m, 64));
    }
    if (lane == 0) { rb[wv] = bs; rv[wv] = vs; rc[wv] = ca; }
    __syncthreads();
    if (tid == 0) {
        float sb = 0.f, sv = 0.f, sc = 0.f;
        for (int k = 0; k < 16; ++k) { sb += rb[k]; sv += rv[k]; sc = fmaxf(sc, rc[k]); }
        float tn = (float)tn_p[0];
        out[0] = (sc > 0.f) ? (sv + sb) / tn : 0.0f;
    }
}

extern "C" void kernel_launch(void* const* d_in, const int* in_sizes, int n_in,
                              void* d_out, int out_size, void* d_ws, size_t ws_size,
                              hipStream_t stream) {
    const float* s_logits = (const float*)d_in[0];
    const float* s_boxes  = (const float*)d_in[1];
    const float* t_logits = (const float*)d_in[2];
    const float* t_boxes  = (const float*)d_in[3];
    const int*   tn       = (const int*)d_in[4];
    float* out = (float*)d_out;

    char* ws = (char*)d_ws;
    int*    g_cnt  = (int*)(ws);              // 14400 i32 @ 0 (zeroed per call)
    float*  g_v    = (float*)(ws + 57600);    // 14400 f32
    float2* g_part = (float2*)(ws + 115200);  // 912 float2

    hipMemsetAsync(g_cnt, 0, NB * NQ * sizeof(int), stream);
    k_main<<<dim3(CHB, NB), 256, 0, stream>>>(s_logits, s_boxes, t_logits, t_boxes,
                                              g_cnt, g_v, g_part);
    k_final<<<1, 1024, 0, stream>>>(g_cnt, g_v, g_part, tn, out);
}